// Round 3
// baseline (226.047 us; speedup 1.0000x reference)
//
#include <hip/hip_runtime.h>
#include <hip/hip_bf16.h>

// SelectiveSSM: B=1, L=2048, D_MODEL=512, D_INNER=1024, D_STATE=16, D_CONV=4
// ESTABLISHED: inputs fp32, d_out fp32, ws >= 17.05MB (R6 fp32 path ran).
// R16 (262us): 64-tile GEMMs, conv+transpose fused, 9 launches.
// R17 (216us): scan serial-chain removal via exclusive log-prefix P[k] in regs.
// R18 (226us, FAILED): t[k] cache spilled to scratch (VGPR capped 64 by bare
// launch_bounds; WRITE 14->91MB) + PSX 516 broke the 513-stride conflict-free
// sxpT reads (bank conflicts x12). Store/staging merge untestable under the
// spill confound.
// R19: revert to R17 memory structure (PSX 513, scalar sxpT staging, store in
// own interval at chunk end); keep balanced pass B + t[k] cache; fix spill via
// __launch_bounds__(1024,4) -> VGPR cap 128 (occupancy already LDS-bound at
// 16 waves/CU, so no occupancy cost).
// ws 16.27MB: xz 8MB@0 | buf1 4MB@8 | shared 4MB@12 (WinT 2MB -> xsT 4MB ->
// WoutT 1MB) | xpcT 270KB@16MB.

#define L_SEQ 2048
#define DM 512
#define DI 1024
#define DS 16
#define NXP 33
#define EPS 1e-10f
#define RCPEPS 1e10f
#define LOG2E 1.44269504088896340736f
#define LN2 0.69314718055994530942f
#define LOG2EPS -33.219280948873623478f  // log2(1e-10)

typedef __hip_bfloat16 bf16;
typedef __attribute__((ext_vector_type(8))) short bf16x8v;
typedef __attribute__((ext_vector_type(4))) float f32x4v;
typedef __attribute__((ext_vector_type(4))) unsigned int u32x4v;

__device__ __forceinline__ float ldf(const float* p) { return *p; }
__device__ __forceinline__ float ldf(const bf16* p) { return __bfloat162float(*p); }

__device__ __forceinline__ void st1(float* p, float v) { *p = v; }
__device__ __forceinline__ void st1(bf16* p, float v) { *p = __float2bfloat16(v); }

__device__ __forceinline__ float fexp2(float x) { return __builtin_amdgcn_exp2f(x); }
__device__ __forceinline__ float frcp(float x) { return __builtin_amdgcn_rcpf(x); }

__device__ __forceinline__ void load8(const float* p, float* v) {
  float4 a = *(const float4*)p;
  float4 b = *(const float4*)(p + 4);
  v[0] = a.x; v[1] = a.y; v[2] = a.z; v[3] = a.w;
  v[4] = b.x; v[5] = b.y; v[6] = b.z; v[7] = b.w;
}
__device__ __forceinline__ void load8(const bf16* p, float* v) {
  bf16 t[8];
  *(uint4*)t = *(const uint4*)p;
#pragma unroll
  for (int j = 0; j < 8; ++j) v[j] = __bfloat162float(t[j]);
}

// W[R][C] fp32 -> WT[C][R] bf16, 32x32 LDS tiles. grid (C/32, R/32), 256 thr.
__global__ __launch_bounds__(256)
void transpose_cast_kernel(const float* __restrict__ W, bf16* __restrict__ WT,
                           int R, int C) {
  __shared__ float tile[32][33];
  int c0 = blockIdx.x * 32, r0 = blockIdx.y * 32;
  int tx = threadIdx.x & 31, ty = threadIdx.x >> 5;
#pragma unroll
  for (int i = 0; i < 4; ++i) {
    int rr = ty + i * 8;
    tile[rr][tx] = W[(size_t)(r0 + rr) * C + c0 + tx];
  }
  __syncthreads();
#pragma unroll
  for (int i = 0; i < 4; ++i) {
    int cc = ty + i * 8;
    WT[(size_t)(c0 + cc) * R + r0 + tx] = __float2bfloat16(tile[tx][cc]);
  }
}

// ---------- 64-tile MFMA GEMM: C[M][N] = A[M][K] @ BT[N][K]^T ----------
// A: fp32 (cast-on-stage, contiguous) or bf16. BT: bf16 rows of length K.
template <typename TA, typename TC>
__global__ __launch_bounds__(256)
void gemm_bt64(const TA* __restrict__ A, const bf16* __restrict__ BT,
               TC* __restrict__ C, int M, int N, int K, int lda, int ldc) {
  __shared__ __align__(16) bf16 As[64 * 40];
  __shared__ __align__(16) bf16 Bs[64 * 40];
  const int tid = threadIdx.x;
  const int wave = tid >> 6, lane = tid & 63;
  const int q = lane >> 4, r = lane & 15;
  const int row0 = blockIdx.y * 64, col0 = blockIdx.x * 64;
  const int srow = tid >> 2, sseg = tid & 3;
  f32x4v acc[4] = {};
  for (int k0 = 0; k0 < K; k0 += 32) {
    {
      float v[8];
      load8(A + (size_t)(row0 + srow) * lda + k0 + sseg * 8, v);
      bf16* dst = &As[srow * 40 + sseg * 8];
#pragma unroll
      for (int j = 0; j < 8; ++j) dst[j] = __float2bfloat16(v[j]);
    }
    *(uint4*)&Bs[srow * 40 + sseg * 8] =
        *(const uint4*)(BT + (size_t)(col0 + srow) * K + k0 + sseg * 8);
    __syncthreads();
    bf16x8v a = *(const bf16x8v*)&As[(wave * 16 + r) * 40 + q * 8];
#pragma unroll
    for (int j = 0; j < 4; ++j) {
      bf16x8v b = *(const bf16x8v*)&Bs[(j * 16 + r) * 40 + q * 8];
      acc[j] = __builtin_amdgcn_mfma_f32_16x16x32_bf16(a, b, acc[j], 0, 0, 0);
    }
    __syncthreads();
  }
#pragma unroll
  for (int j = 0; j < 4; ++j)
#pragma unroll
    for (int reg = 0; reg < 4; ++reg) {
      int m = row0 + wave * 16 + q * 4 + reg;
      int n = col0 + j * 16 + r;
      st1(C + (size_t)m * ldc + n, acc[j][reg]);
    }
}

// bf16 staging variant of A (direct uint4 copy, no cvt)
template <>
__global__ __launch_bounds__(256)
void gemm_bt64<bf16, float>(const bf16* __restrict__ A, const bf16* __restrict__ BT,
                            float* __restrict__ C, int M, int N, int K,
                            int lda, int ldc) {
  __shared__ __align__(16) bf16 As[64 * 40];
  __shared__ __align__(16) bf16 Bs[64 * 40];
  const int tid = threadIdx.x;
  const int wave = tid >> 6, lane = tid & 63;
  const int q = lane >> 4, r = lane & 15;
  const int row0 = blockIdx.y * 64, col0 = blockIdx.x * 64;
  const int srow = tid >> 2, sseg = tid & 3;
  f32x4v acc[4] = {};
  for (int k0 = 0; k0 < K; k0 += 32) {
    *(uint4*)&As[srow * 40 + sseg * 8] =
        *(const uint4*)(A + (size_t)(row0 + srow) * lda + k0 + sseg * 8);
    *(uint4*)&Bs[srow * 40 + sseg * 8] =
        *(const uint4*)(BT + (size_t)(col0 + srow) * K + k0 + sseg * 8);
    __syncthreads();
    bf16x8v a = *(const bf16x8v*)&As[(wave * 16 + r) * 40 + q * 8];
#pragma unroll
    for (int j = 0; j < 4; ++j) {
      bf16x8v b = *(const bf16x8v*)&Bs[(j * 16 + r) * 40 + q * 8];
      acc[j] = __builtin_amdgcn_mfma_f32_16x16x32_bf16(a, b, acc[j], 0, 0, 0);
    }
    __syncthreads();
  }
#pragma unroll
  for (int j = 0; j < 4; ++j)
#pragma unroll
    for (int reg = 0; reg < 4; ++reg) {
      int m = row0 + wave * 16 + q * 4 + reg;
      int n = col0 + j * 16 + r;
      st1(C + (size_t)m * ldc + n, acc[j][reg]);
    }
}

// ---------- xproj GEMM (R15-proven): xpcT[j][l] = (xs @ W_xproj)[l][j] ----
__global__ __launch_bounds__(256)
void gemm_xproj(const bf16* __restrict__ A, const float* __restrict__ Wx,
                float* __restrict__ xpcT) {
  __shared__ __align__(16) bf16 As[64 * 40];
  __shared__ __align__(16) bf16 Bs[64 * 40];
  const int tid = threadIdx.x;
  const int wave = tid >> 6, lane = tid & 63;
  const int q = lane >> 4, r = lane & 15;
  const int row0 = blockIdx.y * 64;
  const int srow = tid >> 2, sseg = tid & 3;
  f32x4v acc[4] = {};
  for (int k0 = 0; k0 < DI; k0 += 32) {
    *(uint4*)&As[srow * 40 + sseg * 8] =
        *(const uint4*)(A + (size_t)(row0 + srow) * DI + k0 + sseg * 8);
    int k = tid >> 3, n0 = (tid & 7) * 8;
#pragma unroll
    for (int j = 0; j < 8; ++j) {
      int n = n0 + j;
      float v = (n < NXP) ? Wx[(size_t)(k0 + k) * NXP + n] : 0.f;
      Bs[n * 40 + k] = __float2bfloat16(v);
    }
    __syncthreads();
    bf16x8v a = *(const bf16x8v*)&As[(wave * 16 + r) * 40 + q * 8];
#pragma unroll
    for (int j = 0; j < 4; ++j) {
      bf16x8v b = *(const bf16x8v*)&Bs[(j * 16 + r) * 40 + q * 8];
      acc[j] = __builtin_amdgcn_mfma_f32_16x16x32_bf16(a, b, acc[j], 0, 0, 0);
    }
    __syncthreads();
  }
#pragma unroll
  for (int j = 0; j < 4; ++j)
#pragma unroll
    for (int reg = 0; reg < 4; ++reg) {
      int m = row0 + wave * 16 + q * 4 + reg;
      int n = j * 16 + r;
      if (n < NXP) xpcT[(size_t)n * L_SEQ + m] = acc[j][reg];
    }
}

// ---------- conv + silu, dual-layout output ----------
// Reads xz x-half (ld 2048), writes xs to buf1[l][d] and xsT[d][l].
// grid (DI/64, L/64), 256 threads. Causal width-4 conv along l.
__global__ __launch_bounds__(256)
void conv_silu_dual(const bf16* __restrict__ xz, const float* __restrict__ conv_w,
                    const float* __restrict__ conv_b, bf16* __restrict__ xs,
                    bf16* __restrict__ xsT) {
  __shared__ bf16 tile[67][72];   // rows l0-3 .. l0+63
  __shared__ bf16 sout[64][72];   // [d][l]
  const int tid = threadIdx.x;
  const int d0 = blockIdx.x * 64, l0 = blockIdx.y * 64;
  // stage 67 rows x 64 cols
  for (int slot = tid; slot < 67 * 8; slot += 256) {
    int rr = slot >> 3, seg = slot & 7;
    int l = l0 - 3 + rr;
    uint4 v = {0, 0, 0, 0};
    if (l >= 0) v = *(const uint4*)(xz + (size_t)l * (2 * DI) + d0 + seg * 8);
    *(uint4*)&tile[rr][seg * 8] = v;
  }
  __syncthreads();
  // compute: thread -> 2 rows x 8 cols
  {
    int lr = tid >> 3, c0t = (tid & 7) * 8;
#pragma unroll
    for (int half = 0; half < 2; ++half) {
      int lrow = lr + half * 32;
      bf16 o[8];
#pragma unroll
      for (int j = 0; j < 8; ++j) {
        int c = c0t + j;
        float acc = conv_b[d0 + c];
#pragma unroll
        for (int k = 0; k < 4; ++k)
          acc = fmaf(__bfloat162float(tile[lrow + k][c]), conv_w[(d0 + c) * 4 + k], acc);
        float v = acc / (1.f + __expf(-acc));
        o[j] = __float2bfloat16(v);
        sout[c][lrow] = o[j];
      }
      *(uint4*)(xs + (size_t)(l0 + lrow) * DI + d0 + c0t) = *(uint4*)o;
    }
  }
  __syncthreads();
  for (int slot = tid; slot < 64 * 8; slot += 256) {
    int dd = slot >> 3, seg = slot & 7;
    *(uint4*)(xsT + (size_t)(d0 + dd) * L_SEQ + l0 + seg * 8) =
        *(uint4*)&sout[dd][seg * 8];
  }
}

// ys[l][d] = yT[d][l] * silu(z[l][d]); z has leading dim ldz.
__global__ __launch_bounds__(256)
void gate_transpose_kernel(const bf16* __restrict__ yT, const bf16* __restrict__ zbuf,
                           int ldz, bf16* __restrict__ ys) {
  __shared__ bf16 tile[64][72];
  int d0 = blockIdx.y * 64, l0 = blockIdx.x * 64;
#pragma unroll
  for (int it = 0; it < 2; ++it) {
    int slot = threadIdx.x + it * 256;
    int dd = slot >> 3, seg = slot & 7;
    *(uint4*)&tile[dd][seg * 8] = *(const uint4*)(yT + (size_t)(d0 + dd) * L_SEQ + l0 + seg * 8);
  }
  __syncthreads();
#pragma unroll
  for (int it = 0; it < 2; ++it) {
    int slot = threadIdx.x + it * 256;
    int ll = slot >> 3, seg = slot & 7;
    bf16 zt[8];
    *(uint4*)zt = *(const uint4*)(zbuf + (size_t)(l0 + ll) * ldz + d0 + seg * 8);
    bf16 o[8];
#pragma unroll
    for (int j = 0; j < 8; ++j) {
      float yv = __bfloat162float(tile[seg * 8 + j][ll]);
      float zv = __bfloat162float(zt[j]);
      o[j] = __float2bfloat16(yv * zv * frcp(1.f + fexp2(-zv * LOG2E)));
    }
    *(uint4*)(ys + (size_t)(l0 + ll) * DI + d0 + seg * 8) = *(uint4*)o;
  }
}

// ---------- chunk-parallel scan ----------
// R17: exclusive log-prefix P[k] in registers (no transcendental serial chain).
// R19: PSX=513 (513 mod 32 = 1 -> s-indexed row reads hit 16 distinct banks,
// conflict-free); scalar sxpT staging; store in own interval at chunk end;
// balanced pass B; t[k] E->G cache held in registers via launch_bounds(1024,4)
// (VGPR cap 128; occupancy already LDS-bound at 16 waves/CU).
#define LC 512
#define NW 16
#define SPW 32
#define PSX 513
#define LCP 516

__global__ __launch_bounds__(1024, 4)
void scan_kernel(bf16* __restrict__ xsT, const float* __restrict__ xpcT,
                 const float* __restrict__ dt_w, const float* __restrict__ dt_b,
                 const float* __restrict__ A_log, const float* __restrict__ Dvec) {
  __shared__ float sxpT[NXP * PSX];
  __shared__ float sdt[4 * LCP], sg[4 * LCP], sxs[4 * LCP];
  __shared__ float sys[4 * LCP];
  __shared__ float Wtot[NW][64], Vtot[NW][64];
  const int tid = threadIdx.x;
  const int wave = tid >> 6, lane = tid & 63;
  const int s = lane & 15, dl = lane >> 4;
  const int d0 = blockIdx.x * 4;
  const int base = wave * SPW;
  const float As2 = -expf(A_log[s]) * LOG2E;
  const float Dd = Dvec[d0 + dl];
  float dtw[4], dtb[4];
#pragma unroll
  for (int c = 0; c < 4; ++c) {
    dtw[c] = dt_w[d0 + c];
    dtb[c] = dt_b[d0 + c];
  }
  float cs2_carry = 0.f, S_carry = 0.f;
  for (int l0 = 0; l0 < L_SEQ; l0 += LC) {
    // ---- stage xpcT chunk (scalar: conflict-free 513-stride) and xs chunk ----
    for (int idx = tid; idx < NXP * LC; idx += 1024) {
      int j = idx >> 9, l = idx & (LC - 1);
      sxpT[j * PSX + l] = xpcT[(size_t)j * L_SEQ + l0 + l];
    }
    for (int slot = tid; slot < 4 * (LC / 8); slot += 1024) {
      int c = slot >> 6, seg = slot & 63;
      bf16 tmp[8];
      *(uint4*)tmp = *(const uint4*)(xsT + (size_t)(d0 + c) * L_SEQ + l0 + seg * 8);
#pragma unroll
      for (int j = 0; j < 8; ++j) sxs[c * LCP + seg * 8 + j] = __bfloat162float(tmp[j]);
    }
    __syncthreads();
    // ---- pass B: dt + g, all 1024 threads (2 cells each) ----
    for (int idx = tid; idx < 4 * LC; idx += 1024) {
      int c = idx >> 9, i = idx & (LC - 1);
      float x0 = sxpT[i];
      float a = fmaf(x0, dtw[c], dtb[c]);
      float dt = __log2f(1.f + fexp2(a * LOG2E)) * LN2;
      sdt[c * LCP + i] = dt;
      sg[c * LCP + i] = dt * sxs[c * LCP + i];
    }
    __syncthreads();
    // ---- pass C: exclusive prefix of clamped log2 A_bar ----
    float P[SPW];
    float Wl = 0.f;
#pragma unroll
    for (int k = 0; k < SPW; ++k) {
      float u = sdt[dl * LCP + base + k] * As2;
      P[k] = Wl;                       // exclusive prefix
      Wl += fmaxf(u, LOG2EPS);
    }
    Wtot[wave][lane] = Wl;
    __syncthreads();
    float O = cs2_carry, Wall = 0.f;
    for (int w = 0; w < NW; ++w) {
      float t = Wtot[w][lane];
      if (w < wave) O += t;
      Wall += t;
    }
    // ---- pass E: V partial sums; cache update terms t[k] for pass G ----
    float t[SPW];
    float Vl = 0.f;
#pragma unroll
    for (int k = 0; k < SPW; ++k) {
      float rcpA = fminf(fexp2(-(O + P[k])), RCPEPS);
      float gb = sg[dl * LCP + base + k] * sxpT[(1 + s) * PSX + base + k];
      t[k] = gb * rcpA;
      Vl += t[k];
    }
    Vtot[wave][lane] = Vl;
    __syncthreads();
    float SO = S_carry, Vall = 0.f;
    for (int w = 0; w < NW; ++w) {
      float tv = Vtot[w][lane];
      if (w < wave) SO += tv;
      Vall += tv;
    }
    // ---- pass G: h_k = exp2(O+P_k) * S_k (telescoped) ----
    float S = SO;
#pragma unroll
    for (int k = 0; k < SPW; ++k) {
      S += t[k];
      float h = fexp2(O + P[k]) * S;
      float contrib = sxpT[(17 + s) * PSX + base + k] * h;
      contrib += __shfl_xor(contrib, 8);
      contrib += __shfl_xor(contrib, 4);
      contrib += __shfl_xor(contrib, 2);
      contrib += __shfl_xor(contrib, 1);
      if (s == 0)
        sys[dl * LCP + base + k] = contrib + Dd * sxs[dl * LCP + base + k];
    }
    cs2_carry += Wall;
    S_carry += Vall;
    __syncthreads();
    // ---- store sys (own interval; nontemporal) ----
    for (int slot = tid; slot < 4 * (LC / 8); slot += 1024) {
      int c = slot >> 6, seg = slot & 63;
      bf16 tmp[8];
#pragma unroll
      for (int j = 0; j < 8; ++j) tmp[j] = __float2bfloat16(sys[c * LCP + seg * 8 + j]);
      u32x4v vv;
      vv.x = ((unsigned int*)tmp)[0]; vv.y = ((unsigned int*)tmp)[1];
      vv.z = ((unsigned int*)tmp)[2]; vv.w = ((unsigned int*)tmp)[3];
      __builtin_nontemporal_store(vv,
          (u32x4v*)(xsT + (size_t)(d0 + c) * L_SEQ + l0 + seg * 8));
    }
    __syncthreads();
  }
}

extern "C" void kernel_launch(void* const* d_in, const int* in_sizes, int n_in,
                              void* d_out, int out_size, void* d_ws, size_t ws_size,
                              hipStream_t stream) {
  const float* x       = (const float*)d_in[0];
  const float* W_in    = (const float*)d_in[1];
  const float* conv_w  = (const float*)d_in[2];
  const float* conv_b  = (const float*)d_in[3];
  const float* W_xproj = (const float*)d_in[4];
  const float* dt_w    = (const float*)d_in[5];
  const float* dt_b    = (const float*)d_in[6];
  const float* A_log   = (const float*)d_in[7];
  const float* Dvec    = (const float*)d_in[8];
  const float* W_out   = (const float*)d_in[9];
  float* out = (float*)d_out;

  char* ws = (char*)d_ws;
  const size_t MB = 1024 * 1024;
  bf16* xz    = (bf16*)(ws);             // [2048][2048]
  bf16* buf1  = (bf16*)(ws + 8 * MB);    // [2048][1024] xs, later gated ys
  bf16* WinT  = (bf16*)(ws + 12 * MB);   // [2048][512] (dead after gemm1)
  bf16* xsT   = (bf16*)(ws + 12 * MB);   // [1024][2048] overlays WinT
  bf16* WoutT = (bf16*)(ws + 12 * MB);   // [512][1024] overlays dead xsT (late)
  float* xpcT = (float*)(ws + 16 * MB);  // [33][2048]

  // 1) WinT = W_in^T bf16
  transpose_cast_kernel<<<dim3(2 * DI / 32, DM / 32), 256, 0, stream>>>(
      W_in, WinT, DM, 2 * DI);
  // 2) xz = x @ W_in  (full N=2048; A fp32 cast-on-stage)
  gemm_bt64<float, bf16><<<dim3(2 * DI / 64, L_SEQ / 64), 256, 0, stream>>>(
      x, WinT, xz, L_SEQ, 2 * DI, DM, DM, 2 * DI);
  // 3) conv + silu -> buf1[l][d] AND xsT[d][l]  (WinT dead)
  conv_silu_dual<<<dim3(DI / 64, L_SEQ / 64), 256, 0, stream>>>(
      xz, conv_w, conv_b, buf1, xsT);
  // 4) xpcT = (xs @ W_xproj)^T
  gemm_xproj<<<dim3(1, L_SEQ / 64), 256, 0, stream>>>(buf1, W_xproj, xpcT);
  // 5) scan: un-gated yT in place over xsT
  scan_kernel<<<DI / 4, 1024, 0, stream>>>(xsT, xpcT, dt_w, dt_b, A_log, Dvec);
  // 6) gate + transpose: ys[l][d] = yT * silu(z), z = xz cols 1024.. (ld 2048)
  gate_transpose_kernel<<<dim3(L_SEQ / 64, DI / 64), 256, 0, stream>>>(
      xsT, xz + DI, 2 * DI, buf1);
  // 7) WoutT = W_out^T bf16 (xsT dead now)
  transpose_cast_kernel<<<dim3(DM / 32, DI / 32), 256, 0, stream>>>(
      W_out, WoutT, DI, DM);
  // 8) out = ys @ W_out
  gemm_bt64<bf16, float><<<dim3(DM / 64, L_SEQ / 64), 256, 0, stream>>>(
      buf1, WoutT, out, L_SEQ, DM, DI, DI, DM);
}

// Round 4
// 221.442 us; speedup vs baseline: 1.0208x; 1.0208x over previous
//
#include <hip/hip_runtime.h>
#include <hip/hip_bf16.h>

// SelectiveSSM: B=1, L=2048, D_MODEL=512, D_INNER=1024, D_STATE=16, D_CONV=4
// ESTABLISHED: inputs fp32, d_out fp32, ws >= 17.05MB (R6 fp32 path ran).
// R16 (262us): 64-tile GEMMs, conv+transpose fused, 9 launches.
// R17 (216us): scan serial-chain removal via exclusive log-prefix P[k] in regs.
// R18 (226us, FAILED): t[k] cache spilled (WRITE 14->91MB); PSX 516 broke
// conflict-free sxpT (x12 conflicts).
// R19 (226us, FAILED): launch_bounds(1024,4) did NOT raise VGPR cap (still 64,
// WRITE 60MB spill persists); also added a 6th barrier serializing store vs
// next staging. PSX=513 restored conflict-free reads (98K, confirmed).
// R20: abandon t[] cache (not worth 32 regs). Exact R17 E/G + balanced B +
// 5 barriers/chunk (store shares interval with next staging) + sxpT staging
// via global_load_lds (wave-uniform LDS base, per-lane global src; no VGPR
// round-trip). GEMM1 switched to bf16 A via a tiny x-cast kernel (kills the
// 8x ds_write_b16 cast-on-stage path).
// ws 16.27MB: xz 8MB@0 | buf1 4MB@8 | shared 4MB@12 (WinT 2MB + xbf 2MB@14 ->
// xsT 4MB -> WoutT 1MB) | xpcT 270KB@16MB.

#define L_SEQ 2048
#define DM 512
#define DI 1024
#define DS 16
#define NXP 33
#define EPS 1e-10f
#define RCPEPS 1e10f
#define LOG2E 1.44269504088896340736f
#define LN2 0.69314718055994530942f
#define LOG2EPS -33.219280948873623478f  // log2(1e-10)

typedef __hip_bfloat16 bf16;
typedef __attribute__((ext_vector_type(8))) short bf16x8v;
typedef __attribute__((ext_vector_type(4))) float f32x4v;
typedef __attribute__((ext_vector_type(4))) unsigned int u32x4v;

__device__ __forceinline__ float ldf(const float* p) { return *p; }
__device__ __forceinline__ float ldf(const bf16* p) { return __bfloat162float(*p); }

__device__ __forceinline__ void st1(float* p, float v) { *p = v; }
__device__ __forceinline__ void st1(bf16* p, float v) { *p = __float2bfloat16(v); }

__device__ __forceinline__ float fexp2(float x) { return __builtin_amdgcn_exp2f(x); }
__device__ __forceinline__ float frcp(float x) { return __builtin_amdgcn_rcpf(x); }

__device__ __forceinline__ void load8(const float* p, float* v) {
  float4 a = *(const float4*)p;
  float4 b = *(const float4*)(p + 4);
  v[0] = a.x; v[1] = a.y; v[2] = a.z; v[3] = a.w;
  v[4] = b.x; v[5] = b.y; v[6] = b.z; v[7] = b.w;
}
__device__ __forceinline__ void load8(const bf16* p, float* v) {
  bf16 t[8];
  *(uint4*)t = *(const uint4*)p;
#pragma unroll
  for (int j = 0; j < 8; ++j) v[j] = __bfloat162float(t[j]);
}

// W[R][C] fp32 -> WT[C][R] bf16, 32x32 LDS tiles. grid (C/32, R/32), 256 thr.
__global__ __launch_bounds__(256)
void transpose_cast_kernel(const float* __restrict__ W, bf16* __restrict__ WT,
                           int R, int C) {
  __shared__ float tile[32][33];
  int c0 = blockIdx.x * 32, r0 = blockIdx.y * 32;
  int tx = threadIdx.x & 31, ty = threadIdx.x >> 5;
#pragma unroll
  for (int i = 0; i < 4; ++i) {
    int rr = ty + i * 8;
    tile[rr][tx] = W[(size_t)(r0 + rr) * C + c0 + tx];
  }
  __syncthreads();
#pragma unroll
  for (int i = 0; i < 4; ++i) {
    int cc = ty + i * 8;
    WT[(size_t)(c0 + cc) * R + r0 + tx] = __float2bfloat16(tile[tx][cc]);
  }
}

// fp32 -> bf16 flat cast, 8 elems/thread. grid = n/(256*8).
__global__ __launch_bounds__(256)
void cast_f32_bf16_kernel(const float* __restrict__ src, bf16* __restrict__ dst,
                          int n8) {
  int i = blockIdx.x * 256 + threadIdx.x;
  if (i < n8) {
    float v[8];
    load8(src + (size_t)i * 8, v);
    bf16 o[8];
#pragma unroll
    for (int j = 0; j < 8; ++j) o[j] = __float2bfloat16(v[j]);
    *(uint4*)(dst + (size_t)i * 8) = *(uint4*)o;
  }
}

// ---------- 64-tile MFMA GEMM: C[M][N] = A[M][K] @ BT[N][K]^T ----------
// A: bf16 (uint4 copy) or fp32 (cast-on-stage). BT: bf16 rows of length K.
template <typename TA, typename TC>
__global__ __launch_bounds__(256)
void gemm_bt64(const TA* __restrict__ A, const bf16* __restrict__ BT,
               TC* __restrict__ C, int M, int N, int K, int lda, int ldc) {
  __shared__ __align__(16) bf16 As[64 * 40];
  __shared__ __align__(16) bf16 Bs[64 * 40];
  const int tid = threadIdx.x;
  const int wave = tid >> 6, lane = tid & 63;
  const int q = lane >> 4, r = lane & 15;
  const int row0 = blockIdx.y * 64, col0 = blockIdx.x * 64;
  const int srow = tid >> 2, sseg = tid & 3;
  f32x4v acc[4] = {};
  for (int k0 = 0; k0 < K; k0 += 32) {
    if constexpr (sizeof(TA) == 2) {
      *(uint4*)&As[srow * 40 + sseg * 8] =
          *(const uint4*)(A + (size_t)(row0 + srow) * lda + k0 + sseg * 8);
    } else {
      float v[8];
      load8(A + (size_t)(row0 + srow) * lda + k0 + sseg * 8, v);
      bf16* dst = &As[srow * 40 + sseg * 8];
#pragma unroll
      for (int j = 0; j < 8; ++j) dst[j] = __float2bfloat16(v[j]);
    }
    *(uint4*)&Bs[srow * 40 + sseg * 8] =
        *(const uint4*)(BT + (size_t)(col0 + srow) * K + k0 + sseg * 8);
    __syncthreads();
    bf16x8v a = *(const bf16x8v*)&As[(wave * 16 + r) * 40 + q * 8];
#pragma unroll
    for (int j = 0; j < 4; ++j) {
      bf16x8v b = *(const bf16x8v*)&Bs[(j * 16 + r) * 40 + q * 8];
      acc[j] = __builtin_amdgcn_mfma_f32_16x16x32_bf16(a, b, acc[j], 0, 0, 0);
    }
    __syncthreads();
  }
#pragma unroll
  for (int j = 0; j < 4; ++j)
#pragma unroll
    for (int reg = 0; reg < 4; ++reg) {
      int m = row0 + wave * 16 + q * 4 + reg;
      int n = col0 + j * 16 + r;
      st1(C + (size_t)m * ldc + n, acc[j][reg]);
    }
}

// ---------- xproj GEMM (R15-proven): xpcT[j][l] = (xs @ W_xproj)[l][j] ----
__global__ __launch_bounds__(256)
void gemm_xproj(const bf16* __restrict__ A, const float* __restrict__ Wx,
                float* __restrict__ xpcT) {
  __shared__ __align__(16) bf16 As[64 * 40];
  __shared__ __align__(16) bf16 Bs[64 * 40];
  const int tid = threadIdx.x;
  const int wave = tid >> 6, lane = tid & 63;
  const int q = lane >> 4, r = lane & 15;
  const int row0 = blockIdx.y * 64;
  const int srow = tid >> 2, sseg = tid & 3;
  f32x4v acc[4] = {};
  for (int k0 = 0; k0 < DI; k0 += 32) {
    *(uint4*)&As[srow * 40 + sseg * 8] =
        *(const uint4*)(A + (size_t)(row0 + srow) * DI + k0 + sseg * 8);
    int k = tid >> 3, n0 = (tid & 7) * 8;
#pragma unroll
    for (int j = 0; j < 8; ++j) {
      int n = n0 + j;
      float v = (n < NXP) ? Wx[(size_t)(k0 + k) * NXP + n] : 0.f;
      Bs[n * 40 + k] = __float2bfloat16(v);
    }
    __syncthreads();
    bf16x8v a = *(const bf16x8v*)&As[(wave * 16 + r) * 40 + q * 8];
#pragma unroll
    for (int j = 0; j < 4; ++j) {
      bf16x8v b = *(const bf16x8v*)&Bs[(j * 16 + r) * 40 + q * 8];
      acc[j] = __builtin_amdgcn_mfma_f32_16x16x32_bf16(a, b, acc[j], 0, 0, 0);
    }
    __syncthreads();
  }
#pragma unroll
  for (int j = 0; j < 4; ++j)
#pragma unroll
    for (int reg = 0; reg < 4; ++reg) {
      int m = row0 + wave * 16 + q * 4 + reg;
      int n = j * 16 + r;
      if (n < NXP) xpcT[(size_t)n * L_SEQ + m] = acc[j][reg];
    }
}

// ---------- conv + silu, dual-layout output ----------
// Reads xz x-half (ld 2048), writes xs to buf1[l][d] and xsT[d][l].
// grid (DI/64, L/64), 256 threads. Causal width-4 conv along l.
__global__ __launch_bounds__(256)
void conv_silu_dual(const bf16* __restrict__ xz, const float* __restrict__ conv_w,
                    const float* __restrict__ conv_b, bf16* __restrict__ xs,
                    bf16* __restrict__ xsT) {
  __shared__ bf16 tile[67][72];   // rows l0-3 .. l0+63
  __shared__ bf16 sout[64][72];   // [d][l]
  const int tid = threadIdx.x;
  const int d0 = blockIdx.x * 64, l0 = blockIdx.y * 64;
  // stage 67 rows x 64 cols
  for (int slot = tid; slot < 67 * 8; slot += 256) {
    int rr = slot >> 3, seg = slot & 7;
    int l = l0 - 3 + rr;
    uint4 v = {0, 0, 0, 0};
    if (l >= 0) v = *(const uint4*)(xz + (size_t)l * (2 * DI) + d0 + seg * 8);
    *(uint4*)&tile[rr][seg * 8] = v;
  }
  __syncthreads();
  // compute: thread -> 2 rows x 8 cols
  {
    int lr = tid >> 3, c0t = (tid & 7) * 8;
#pragma unroll
    for (int half = 0; half < 2; ++half) {
      int lrow = lr + half * 32;
      bf16 o[8];
#pragma unroll
      for (int j = 0; j < 8; ++j) {
        int c = c0t + j;
        float acc = conv_b[d0 + c];
#pragma unroll
        for (int k = 0; k < 4; ++k)
          acc = fmaf(__bfloat162float(tile[lrow + k][c]), conv_w[(d0 + c) * 4 + k], acc);
        float v = acc / (1.f + __expf(-acc));
        o[j] = __float2bfloat16(v);
        sout[c][lrow] = o[j];
      }
      *(uint4*)(xs + (size_t)(l0 + lrow) * DI + d0 + c0t) = *(uint4*)o;
    }
  }
  __syncthreads();
  for (int slot = tid; slot < 64 * 8; slot += 256) {
    int dd = slot >> 3, seg = slot & 7;
    *(uint4*)(xsT + (size_t)(d0 + dd) * L_SEQ + l0 + seg * 8) =
        *(uint4*)&sout[dd][seg * 8];
  }
}

// ys[l][d] = yT[d][l] * silu(z[l][d]); z has leading dim ldz.
__global__ __launch_bounds__(256)
void gate_transpose_kernel(const bf16* __restrict__ yT, const bf16* __restrict__ zbuf,
                           int ldz, bf16* __restrict__ ys) {
  __shared__ bf16 tile[64][72];
  int d0 = blockIdx.y * 64, l0 = blockIdx.x * 64;
#pragma unroll
  for (int it = 0; it < 2; ++it) {
    int slot = threadIdx.x + it * 256;
    int dd = slot >> 3, seg = slot & 7;
    *(uint4*)&tile[dd][seg * 8] = *(const uint4*)(yT + (size_t)(d0 + dd) * L_SEQ + l0 + seg * 8);
  }
  __syncthreads();
#pragma unroll
  for (int it = 0; it < 2; ++it) {
    int slot = threadIdx.x + it * 256;
    int ll = slot >> 3, seg = slot & 7;
    bf16 zt[8];
    *(uint4*)zt = *(const uint4*)(zbuf + (size_t)(l0 + ll) * ldz + d0 + seg * 8);
    bf16 o[8];
#pragma unroll
    for (int j = 0; j < 8; ++j) {
      float yv = __bfloat162float(tile[seg * 8 + j][ll]);
      float zv = __bfloat162float(zt[j]);
      o[j] = __float2bfloat16(yv * zv * frcp(1.f + fexp2(-zv * LOG2E)));
    }
    *(uint4*)(ys + (size_t)(l0 + ll) * DI + d0 + seg * 8) = *(uint4*)o;
  }
}

// ---------- chunk-parallel scan ----------
// R17 structure (proven VGPR 64, no spill): P[32] only; G recomputes gb/rcpA.
// R20: sxpT staged via global_load_lds (wave-uniform LDS base + lane*4;
// per-lane global src); store shares interval with next chunk's staging.
#define LC 512
#define NW 16
#define SPW 32
#define PSX 513
#define LCP 516

__global__ __launch_bounds__(1024)
void scan_kernel(bf16* __restrict__ xsT, const float* __restrict__ xpcT,
                 const float* __restrict__ dt_w, const float* __restrict__ dt_b,
                 const float* __restrict__ A_log, const float* __restrict__ Dvec) {
  __shared__ float sxpT[NXP * PSX];
  __shared__ float sdt[4 * LCP], sg[4 * LCP], sxs[4 * LCP];
  __shared__ float sys[4 * LCP];
  __shared__ float Wtot[NW][64], Vtot[NW][64];
  const int tid = threadIdx.x;
  const int wave = tid >> 6, lane = tid & 63;
  const int s = lane & 15, dl = lane >> 4;
  const int d0 = blockIdx.x * 4;
  const int base = wave * SPW;
  const float As2 = -expf(A_log[s]) * LOG2E;
  const float Dd = Dvec[d0 + dl];
  float dtw[4], dtb[4];
#pragma unroll
  for (int c = 0; c < 4; ++c) {
    dtw[c] = dt_w[d0 + c];
    dtb[c] = dt_b[d0 + c];
  }
  float cs2_carry = 0.f, S_carry = 0.f;
  for (int l0 = 0; l0 < L_SEQ; l0 += LC) {
    // ---- stage xpcT chunk via async global->LDS (no VGPR round-trip) ----
    // Wave w, iter i covers idx in [i*1024 + w*64, +64): row j = idx>>9 and
    // column base lb = idx&511 are wave-uniform (64-aligned, never crosses a
    // 512 boundary); lanes are column-consecutive -> LDS dest = base + lane*4.
    for (int idx = tid; idx < NXP * LC; idx += 1024) {
      int u = __builtin_amdgcn_readfirstlane(idx & ~63);
      int j = u >> 9, lb = u & (LC - 1);
      const float* gp = xpcT + (size_t)j * L_SEQ + l0 + lb + lane;
      __builtin_amdgcn_global_load_lds(
          (const __attribute__((address_space(1))) void*)gp,
          (__attribute__((address_space(3))) void*)&sxpT[j * PSX + lb], 4, 0, 0);
    }
    // ---- stage xs chunk ----
    for (int slot = tid; slot < 4 * (LC / 8); slot += 1024) {
      int c = slot >> 6, seg = slot & 63;
      bf16 tmp[8];
      *(uint4*)tmp = *(const uint4*)(xsT + (size_t)(d0 + c) * L_SEQ + l0 + seg * 8);
#pragma unroll
      for (int j = 0; j < 8; ++j) sxs[c * LCP + seg * 8 + j] = __bfloat162float(tmp[j]);
    }
    __syncthreads();
    // ---- pass B: dt + g, all 1024 threads (2 cells each) ----
    for (int idx = tid; idx < 4 * LC; idx += 1024) {
      int c = idx >> 9, i = idx & (LC - 1);
      float x0 = sxpT[i];
      float a = fmaf(x0, dtw[c], dtb[c]);
      float dt = __log2f(1.f + fexp2(a * LOG2E)) * LN2;
      sdt[c * LCP + i] = dt;
      sg[c * LCP + i] = dt * sxs[c * LCP + i];
    }
    __syncthreads();
    // ---- pass C: exclusive prefix of clamped log2 A_bar ----
    float P[SPW];
    float Wl = 0.f;
#pragma unroll
    for (int k = 0; k < SPW; ++k) {
      float u = sdt[dl * LCP + base + k] * As2;
      P[k] = Wl;                       // exclusive prefix
      Wl += fmaxf(u, LOG2EPS);
    }
    Wtot[wave][lane] = Wl;
    __syncthreads();
    float O = cs2_carry, Wall = 0.f;
    for (int w = 0; w < NW; ++w) {
      float t = Wtot[w][lane];
      if (w < wave) O += t;
      Wall += t;
    }
    // ---- pass E: V partial sums ----
    float Vl = 0.f;
#pragma unroll
    for (int k = 0; k < SPW; ++k) {
      float rcpA = fminf(fexp2(-(O + P[k])), RCPEPS);
      float gb = sg[dl * LCP + base + k] * sxpT[(1 + s) * PSX + base + k];
      Vl = fmaf(gb, rcpA, Vl);
    }
    Vtot[wave][lane] = Vl;
    __syncthreads();
    float SO = S_carry, Vall = 0.f;
    for (int w = 0; w < NW; ++w) {
      float tv = Vtot[w][lane];
      if (w < wave) SO += tv;
      Vall += tv;
    }
    // ---- pass G: h_k = exp2(O+P_k) * S_k (telescoped) ----
    float S = SO;
#pragma unroll
    for (int k = 0; k < SPW; ++k) {
      float xk = O + P[k];
      float rcpA = fminf(fexp2(-xk), RCPEPS);
      float aprev = fexp2(xk);
      float gb = sg[dl * LCP + base + k] * sxpT[(1 + s) * PSX + base + k];
      S = fmaf(gb, rcpA, S);
      float h = aprev * S;
      float contrib = sxpT[(17 + s) * PSX + base + k] * h;
      contrib += __shfl_xor(contrib, 8);
      contrib += __shfl_xor(contrib, 4);
      contrib += __shfl_xor(contrib, 2);
      contrib += __shfl_xor(contrib, 1);
      if (s == 0)
        sys[dl * LCP + base + k] = contrib + Dd * sxs[dl * LCP + base + k];
    }
    cs2_carry += Wall;
    S_carry += Vall;
    __syncthreads();
    // ---- store sys (shares interval with next chunk's staging) ----
    for (int slot = tid; slot < 4 * (LC / 8); slot += 1024) {
      int c = slot >> 6, seg = slot & 63;
      bf16 tmp[8];
#pragma unroll
      for (int j = 0; j < 8; ++j) tmp[j] = __float2bfloat16(sys[c * LCP + seg * 8 + j]);
      u32x4v vv;
      vv.x = ((unsigned int*)tmp)[0]; vv.y = ((unsigned int*)tmp)[1];
      vv.z = ((unsigned int*)tmp)[2]; vv.w = ((unsigned int*)tmp)[3];
      __builtin_nontemporal_store(vv,
          (u32x4v*)(xsT + (size_t)(d0 + c) * L_SEQ + l0 + seg * 8));
    }
    // no trailing barrier: store (reads sys) and next staging (writes
    // sxpT/sxs) touch disjoint LDS; next readers are behind 2 barriers.
  }
}

extern "C" void kernel_launch(void* const* d_in, const int* in_sizes, int n_in,
                              void* d_out, int out_size, void* d_ws, size_t ws_size,
                              hipStream_t stream) {
  const float* x       = (const float*)d_in[0];
  const float* W_in    = (const float*)d_in[1];
  const float* conv_w  = (const float*)d_in[2];
  const float* conv_b  = (const float*)d_in[3];
  const float* W_xproj = (const float*)d_in[4];
  const float* dt_w    = (const float*)d_in[5];
  const float* dt_b    = (const float*)d_in[6];
  const float* A_log   = (const float*)d_in[7];
  const float* Dvec    = (const float*)d_in[8];
  const float* W_out   = (const float*)d_in[9];
  float* out = (float*)d_out;

  char* ws = (char*)d_ws;
  const size_t MB = 1024 * 1024;
  bf16* xz    = (bf16*)(ws);             // [2048][2048]
  bf16* buf1  = (bf16*)(ws + 8 * MB);    // [2048][1024] xs, later gated ys
  bf16* WinT  = (bf16*)(ws + 12 * MB);   // [2048][512] (dead after gemm1)
  bf16* xbf   = (bf16*)(ws + 14 * MB);   // [2048][512] x cast (dead after gemm1)
  bf16* xsT   = (bf16*)(ws + 12 * MB);   // [1024][2048] overlays WinT+xbf
  bf16* WoutT = (bf16*)(ws + 12 * MB);   // [512][1024] overlays dead xsT (late)
  float* xpcT = (float*)(ws + 16 * MB);  // [33][2048]

  // 1) WinT = W_in^T bf16; xbf = bf16(x)
  transpose_cast_kernel<<<dim3(2 * DI / 32, DM / 32), 256, 0, stream>>>(
      W_in, WinT, DM, 2 * DI);
  cast_f32_bf16_kernel<<<dim3(L_SEQ * DM / (256 * 8)), 256, 0, stream>>>(
      x, xbf, L_SEQ * DM / 8);
  // 2) xz = x @ W_in  (full N=2048; A bf16 uint4-copy staging)
  gemm_bt64<bf16, bf16><<<dim3(2 * DI / 64, L_SEQ / 64), 256, 0, stream>>>(
      xbf, WinT, xz, L_SEQ, 2 * DI, DM, DM, 2 * DI);
  // 3) conv + silu -> buf1[l][d] AND xsT[d][l]  (WinT, xbf dead)
  conv_silu_dual<<<dim3(DI / 64, L_SEQ / 64), 256, 0, stream>>>(
      xz, conv_w, conv_b, buf1, xsT);
  // 4) xpcT = (xs @ W_xproj)^T
  gemm_xproj<<<dim3(1, L_SEQ / 64), 256, 0, stream>>>(buf1, W_xproj, xpcT);
  // 5) scan: un-gated yT in place over xsT
  scan_kernel<<<DI / 4, 1024, 0, stream>>>(xsT, xpcT, dt_w, dt_b, A_log, Dvec);
  // 6) gate + transpose: ys[l][d] = yT * silu(z), z = xz cols 1024.. (ld 2048)
  gate_transpose_kernel<<<dim3(L_SEQ / 64, DI / 64), 256, 0, stream>>>(
      xsT, xz + DI, 2 * DI, buf1);
  // 7) WoutT = W_out^T bf16 (xsT dead now)
  transpose_cast_kernel<<<dim3(DM / 32, DI / 32), 256, 0, stream>>>(
      W_out, WoutT, DI, DM);
  // 8) out = ys @ W_out
  gemm_bt64<bf16, float><<<dim3(DM / 64, L_SEQ / 64), 256, 0, stream>>>(
      buf1, WoutT, out, L_SEQ, DM, DI, DI, DM);
}

// Round 5
// 218.563 us; speedup vs baseline: 1.0342x; 1.0132x over previous
//
#include <hip/hip_runtime.h>
#include <hip/hip_bf16.h>

// SelectiveSSM: B=1, L=2048, D_MODEL=512, D_INNER=1024, D_STATE=16, D_CONV=4
// ESTABLISHED: inputs fp32, d_out fp32, ws >= 17.05MB (R6 fp32 path ran).
// R16 (262us): 64-tile GEMMs, conv+transpose fused, 9 launches.
// R17 (216us): scan serial-chain removal via exclusive log-prefix P[k] in regs.
// R18/R19 (226us, FAILED): t[k] cache spill fights; reverted.
// R20 (221us): scan back to 62us (spill gone: WRITE 10MB, FETCH 4.8MB);
// global_load_lds sxpT staging + balanced B neutral -> scan at structure floor.
// R21: non-scan 159us dominates. Both big GEMMs rewritten as 2-phase
// double-buffered global_load_lds MFMA (T3-minimum): 1 barrier/K-step,
// staging hidden under MFMA, linear LDS [BM][32] (gload_lds-required),
// fragment math identical to proven 64-tile kernel. gemm1 128x128 grid 256;
// gemm2 64x64 grid 256. Scan/conv/gate/xproj untouched.
// ws 16.27MB: xz 8MB@0 | buf1 4MB@8 | shared 4MB@12 (WinT 2MB + xbf 2MB@14 ->
// xsT 4MB -> WoutT 1MB) | xpcT 270KB@16MB.

#define L_SEQ 2048
#define DM 512
#define DI 1024
#define DS 16
#define NXP 33
#define EPS 1e-10f
#define RCPEPS 1e10f
#define LOG2E 1.44269504088896340736f
#define LN2 0.69314718055994530942f
#define LOG2EPS -33.219280948873623478f  // log2(1e-10)

typedef __hip_bfloat16 bf16;
typedef __attribute__((ext_vector_type(8))) short bf16x8v;
typedef __attribute__((ext_vector_type(4))) float f32x4v;
typedef __attribute__((ext_vector_type(4))) unsigned int u32x4v;

__device__ __forceinline__ void st1(float* p, float v) { *p = v; }
__device__ __forceinline__ void st1(bf16* p, float v) { *p = __float2bfloat16(v); }

__device__ __forceinline__ float fexp2(float x) { return __builtin_amdgcn_exp2f(x); }
__device__ __forceinline__ float frcp(float x) { return __builtin_amdgcn_rcpf(x); }

__device__ __forceinline__ void load8(const float* p, float* v) {
  float4 a = *(const float4*)p;
  float4 b = *(const float4*)(p + 4);
  v[0] = a.x; v[1] = a.y; v[2] = a.z; v[3] = a.w;
  v[4] = b.x; v[5] = b.y; v[6] = b.z; v[7] = b.w;
}

// W[R][C] fp32 -> WT[C][R] bf16, 32x32 LDS tiles. grid (C/32, R/32), 256 thr.
__global__ __launch_bounds__(256)
void transpose_cast_kernel(const float* __restrict__ W, bf16* __restrict__ WT,
                           int R, int C) {
  __shared__ float tile[32][33];
  int c0 = blockIdx.x * 32, r0 = blockIdx.y * 32;
  int tx = threadIdx.x & 31, ty = threadIdx.x >> 5;
#pragma unroll
  for (int i = 0; i < 4; ++i) {
    int rr = ty + i * 8;
    tile[rr][tx] = W[(size_t)(r0 + rr) * C + c0 + tx];
  }
  __syncthreads();
#pragma unroll
  for (int i = 0; i < 4; ++i) {
    int cc = ty + i * 8;
    WT[(size_t)(c0 + cc) * R + r0 + tx] = __float2bfloat16(tile[tx][cc]);
  }
}

// fp32 -> bf16 flat cast, 8 elems/thread. grid = n/(256*8).
__global__ __launch_bounds__(256)
void cast_f32_bf16_kernel(const float* __restrict__ src, bf16* __restrict__ dst,
                          int n8) {
  int i = blockIdx.x * 256 + threadIdx.x;
  if (i < n8) {
    float v[8];
    load8(src + (size_t)i * 8, v);
    bf16 o[8];
#pragma unroll
    for (int j = 0; j < 8; ++j) o[j] = __float2bfloat16(v[j]);
    *(uint4*)(dst + (size_t)i * 8) = *(uint4*)o;
  }
}

// ---------- 2-phase double-buffered gload_lds GEMM ----------
// C[M][N] = A[M][K] @ BT[N][K]^T. A,BT bf16. 256 thr = 4 waves (2x2).
// Per-wave output: (WM*16) x (WN*16). Tile BM=2*WM*16, BN=2*WN*16, BK=32.
// LDS linear [rows][32] bf16 (gload_lds dest = wave base + lane*16).
template <int WM, int WN, typename TC>
__global__ __launch_bounds__(256)
void gemm_gl(const bf16* __restrict__ A, const bf16* __restrict__ BT,
             TC* __restrict__ C, int K, int lda, int ldc) {
  constexpr int BM = 2 * WM * 16, BN = 2 * WN * 16;
  __shared__ __align__(16) bf16 As[2][BM * 32];
  __shared__ __align__(16) bf16 Bs[2][BN * 32];
  const int tid = threadIdx.x;
  const int wave = tid >> 6, lane = tid & 63;
  const int q = lane >> 4, r = lane & 15;
  const int wr = wave >> 1, wc = wave & 1;
  const int row0 = blockIdx.y * BM, col0 = blockIdx.x * BN;
  f32x4v acc[WM][WN] = {};
  const int nt = K / 32;

  auto stage = [&](int buf, int t) {
    int k0 = t * 32;
#pragma unroll
    for (int i = 0; i < BM / 64; ++i) {
      int slot = tid + i * 256;
      int row = slot >> 2, seg = slot & 3;
      __builtin_amdgcn_global_load_lds(
          (const __attribute__((address_space(1))) void*)(
              A + (size_t)(row0 + row) * lda + k0 + seg * 8),
          (__attribute__((address_space(3))) void*)&As[buf][row * 32 + seg * 8],
          16, 0, 0);
    }
#pragma unroll
    for (int i = 0; i < BN / 64; ++i) {
      int slot = tid + i * 256;
      int row = slot >> 2, seg = slot & 3;
      __builtin_amdgcn_global_load_lds(
          (const __attribute__((address_space(1))) void*)(
              BT + (size_t)(col0 + row) * K + k0 + seg * 8),
          (__attribute__((address_space(3))) void*)&Bs[buf][row * 32 + seg * 8],
          16, 0, 0);
    }
  };

  stage(0, 0);
  __syncthreads();  // drains vmcnt(0) before first reads
  int cur = 0;
  for (int t = 0; t < nt; ++t) {
    if (t + 1 < nt) stage(cur ^ 1, t + 1);  // prefetch next tile (other buffer)
    bf16x8v a[WM], b[WN];
#pragma unroll
    for (int m = 0; m < WM; ++m)
      a[m] = *(const bf16x8v*)&As[cur][(wr * WM * 16 + m * 16 + r) * 32 + q * 8];
#pragma unroll
    for (int n = 0; n < WN; ++n)
      b[n] = *(const bf16x8v*)&Bs[cur][(wc * WN * 16 + n * 16 + r) * 32 + q * 8];
#pragma unroll
    for (int m = 0; m < WM; ++m)
#pragma unroll
      for (int n = 0; n < WN; ++n)
        acc[m][n] = __builtin_amdgcn_mfma_f32_16x16x32_bf16(a[m], b[n],
                                                            acc[m][n], 0, 0, 0);
    __syncthreads();  // drains prefetch loads + protects buffer reuse
    cur ^= 1;
  }
#pragma unroll
  for (int m = 0; m < WM; ++m)
#pragma unroll
    for (int n = 0; n < WN; ++n)
#pragma unroll
      for (int reg = 0; reg < 4; ++reg) {
        int mm = row0 + wr * WM * 16 + m * 16 + q * 4 + reg;
        int nn = col0 + wc * WN * 16 + n * 16 + r;
        st1(C + (size_t)mm * ldc + nn, acc[m][n][reg]);
      }
}

// ---------- xproj GEMM (R15-proven): xpcT[j][l] = (xs @ W_xproj)[l][j] ----
__global__ __launch_bounds__(256)
void gemm_xproj(const bf16* __restrict__ A, const float* __restrict__ Wx,
                float* __restrict__ xpcT) {
  __shared__ __align__(16) bf16 As[64 * 40];
  __shared__ __align__(16) bf16 Bs[64 * 40];
  const int tid = threadIdx.x;
  const int wave = tid >> 6, lane = tid & 63;
  const int q = lane >> 4, r = lane & 15;
  const int row0 = blockIdx.y * 64;
  const int srow = tid >> 2, sseg = tid & 3;
  f32x4v acc[4] = {};
  for (int k0 = 0; k0 < DI; k0 += 32) {
    *(uint4*)&As[srow * 40 + sseg * 8] =
        *(const uint4*)(A + (size_t)(row0 + srow) * DI + k0 + sseg * 8);
    int k = tid >> 3, n0 = (tid & 7) * 8;
#pragma unroll
    for (int j = 0; j < 8; ++j) {
      int n = n0 + j;
      float v = (n < NXP) ? Wx[(size_t)(k0 + k) * NXP + n] : 0.f;
      Bs[n * 40 + k] = __float2bfloat16(v);
    }
    __syncthreads();
    bf16x8v a = *(const bf16x8v*)&As[(wave * 16 + r) * 40 + q * 8];
#pragma unroll
    for (int j = 0; j < 4; ++j) {
      bf16x8v b = *(const bf16x8v*)&Bs[(j * 16 + r) * 40 + q * 8];
      acc[j] = __builtin_amdgcn_mfma_f32_16x16x32_bf16(a, b, acc[j], 0, 0, 0);
    }
    __syncthreads();
  }
#pragma unroll
  for (int j = 0; j < 4; ++j)
#pragma unroll
    for (int reg = 0; reg < 4; ++reg) {
      int m = row0 + wave * 16 + q * 4 + reg;
      int n = j * 16 + r;
      if (n < NXP) xpcT[(size_t)n * L_SEQ + m] = acc[j][reg];
    }
}

// ---------- conv + silu, dual-layout output ----------
// Reads xz x-half (ld 2048), writes xs to buf1[l][d] and xsT[d][l].
// grid (DI/64, L/64), 256 threads. Causal width-4 conv along l.
__global__ __launch_bounds__(256)
void conv_silu_dual(const bf16* __restrict__ xz, const float* __restrict__ conv_w,
                    const float* __restrict__ conv_b, bf16* __restrict__ xs,
                    bf16* __restrict__ xsT) {
  __shared__ bf16 tile[67][72];   // rows l0-3 .. l0+63
  __shared__ bf16 sout[64][72];   // [d][l]
  const int tid = threadIdx.x;
  const int d0 = blockIdx.x * 64, l0 = blockIdx.y * 64;
  // stage 67 rows x 64 cols
  for (int slot = tid; slot < 67 * 8; slot += 256) {
    int rr = slot >> 3, seg = slot & 7;
    int l = l0 - 3 + rr;
    uint4 v = {0, 0, 0, 0};
    if (l >= 0) v = *(const uint4*)(xz + (size_t)l * (2 * DI) + d0 + seg * 8);
    *(uint4*)&tile[rr][seg * 8] = v;
  }
  __syncthreads();
  // compute: thread -> 2 rows x 8 cols
  {
    int lr = tid >> 3, c0t = (tid & 7) * 8;
#pragma unroll
    for (int half = 0; half < 2; ++half) {
      int lrow = lr + half * 32;
      bf16 o[8];
#pragma unroll
      for (int j = 0; j < 8; ++j) {
        int c = c0t + j;
        float acc = conv_b[d0 + c];
#pragma unroll
        for (int k = 0; k < 4; ++k)
          acc = fmaf(__bfloat162float(tile[lrow + k][c]), conv_w[(d0 + c) * 4 + k], acc);
        float v = acc / (1.f + __expf(-acc));
        o[j] = __float2bfloat16(v);
        sout[c][lrow] = o[j];
      }
      *(uint4*)(xs + (size_t)(l0 + lrow) * DI + d0 + c0t) = *(uint4*)o;
    }
  }
  __syncthreads();
  for (int slot = tid; slot < 64 * 8; slot += 256) {
    int dd = slot >> 3, seg = slot & 7;
    *(uint4*)(xsT + (size_t)(d0 + dd) * L_SEQ + l0 + seg * 8) =
        *(uint4*)&sout[dd][seg * 8];
  }
}

// ys[l][d] = yT[d][l] * silu(z[l][d]); z has leading dim ldz.
__global__ __launch_bounds__(256)
void gate_transpose_kernel(const bf16* __restrict__ yT, const bf16* __restrict__ zbuf,
                           int ldz, bf16* __restrict__ ys) {
  __shared__ bf16 tile[64][72];
  int d0 = blockIdx.y * 64, l0 = blockIdx.x * 64;
#pragma unroll
  for (int it = 0; it < 2; ++it) {
    int slot = threadIdx.x + it * 256;
    int dd = slot >> 3, seg = slot & 7;
    *(uint4*)&tile[dd][seg * 8] = *(const uint4*)(yT + (size_t)(d0 + dd) * L_SEQ + l0 + seg * 8);
  }
  __syncthreads();
#pragma unroll
  for (int it = 0; it < 2; ++it) {
    int slot = threadIdx.x + it * 256;
    int ll = slot >> 3, seg = slot & 7;
    bf16 zt[8];
    *(uint4*)zt = *(const uint4*)(zbuf + (size_t)(l0 + ll) * ldz + d0 + seg * 8);
    bf16 o[8];
#pragma unroll
    for (int j = 0; j < 8; ++j) {
      float yv = __bfloat162float(tile[seg * 8 + j][ll]);
      float zv = __bfloat162float(zt[j]);
      o[j] = __float2bfloat16(yv * zv * frcp(1.f + fexp2(-zv * LOG2E)));
    }
    *(uint4*)(ys + (size_t)(l0 + ll) * DI + d0 + seg * 8) = *(uint4*)o;
  }
}

// ---------- chunk-parallel scan (R20-proven: 62us, VGPR 64, no spill) ----------
#define LC 512
#define NW 16
#define SPW 32
#define PSX 513
#define LCP 516

__global__ __launch_bounds__(1024)
void scan_kernel(bf16* __restrict__ xsT, const float* __restrict__ xpcT,
                 const float* __restrict__ dt_w, const float* __restrict__ dt_b,
                 const float* __restrict__ A_log, const float* __restrict__ Dvec) {
  __shared__ float sxpT[NXP * PSX];
  __shared__ float sdt[4 * LCP], sg[4 * LCP], sxs[4 * LCP];
  __shared__ float sys[4 * LCP];
  __shared__ float Wtot[NW][64], Vtot[NW][64];
  const int tid = threadIdx.x;
  const int wave = tid >> 6, lane = tid & 63;
  const int s = lane & 15, dl = lane >> 4;
  const int d0 = blockIdx.x * 4;
  const int base = wave * SPW;
  const float As2 = -expf(A_log[s]) * LOG2E;
  const float Dd = Dvec[d0 + dl];
  float dtw[4], dtb[4];
#pragma unroll
  for (int c = 0; c < 4; ++c) {
    dtw[c] = dt_w[d0 + c];
    dtb[c] = dt_b[d0 + c];
  }
  float cs2_carry = 0.f, S_carry = 0.f;
  for (int l0 = 0; l0 < L_SEQ; l0 += LC) {
    // ---- stage xpcT chunk via async global->LDS (no VGPR round-trip) ----
    for (int idx = tid; idx < NXP * LC; idx += 1024) {
      int u = __builtin_amdgcn_readfirstlane(idx & ~63);
      int j = u >> 9, lb = u & (LC - 1);
      const float* gp = xpcT + (size_t)j * L_SEQ + l0 + lb + lane;
      __builtin_amdgcn_global_load_lds(
          (const __attribute__((address_space(1))) void*)gp,
          (__attribute__((address_space(3))) void*)&sxpT[j * PSX + lb], 4, 0, 0);
    }
    // ---- stage xs chunk ----
    for (int slot = tid; slot < 4 * (LC / 8); slot += 1024) {
      int c = slot >> 6, seg = slot & 63;
      bf16 tmp[8];
      *(uint4*)tmp = *(const uint4*)(xsT + (size_t)(d0 + c) * L_SEQ + l0 + seg * 8);
#pragma unroll
      for (int j = 0; j < 8; ++j) sxs[c * LCP + seg * 8 + j] = __bfloat162float(tmp[j]);
    }
    __syncthreads();
    // ---- pass B: dt + g, all 1024 threads (2 cells each) ----
    for (int idx = tid; idx < 4 * LC; idx += 1024) {
      int c = idx >> 9, i = idx & (LC - 1);
      float x0 = sxpT[i];
      float a = fmaf(x0, dtw[c], dtb[c]);
      float dt = __log2f(1.f + fexp2(a * LOG2E)) * LN2;
      sdt[c * LCP + i] = dt;
      sg[c * LCP + i] = dt * sxs[c * LCP + i];
    }
    __syncthreads();
    // ---- pass C: exclusive prefix of clamped log2 A_bar ----
    float P[SPW];
    float Wl = 0.f;
#pragma unroll
    for (int k = 0; k < SPW; ++k) {
      float u = sdt[dl * LCP + base + k] * As2;
      P[k] = Wl;                       // exclusive prefix
      Wl += fmaxf(u, LOG2EPS);
    }
    Wtot[wave][lane] = Wl;
    __syncthreads();
    float O = cs2_carry, Wall = 0.f;
    for (int w = 0; w < NW; ++w) {
      float t = Wtot[w][lane];
      if (w < wave) O += t;
      Wall += t;
    }
    // ---- pass E: V partial sums ----
    float Vl = 0.f;
#pragma unroll
    for (int k = 0; k < SPW; ++k) {
      float rcpA = fminf(fexp2(-(O + P[k])), RCPEPS);
      float gb = sg[dl * LCP + base + k] * sxpT[(1 + s) * PSX + base + k];
      Vl = fmaf(gb, rcpA, Vl);
    }
    Vtot[wave][lane] = Vl;
    __syncthreads();
    float SO = S_carry, Vall = 0.f;
    for (int w = 0; w < NW; ++w) {
      float tv = Vtot[w][lane];
      if (w < wave) SO += tv;
      Vall += tv;
    }
    // ---- pass G: h_k = exp2(O+P_k) * S_k (telescoped) ----
    float S = SO;
#pragma unroll
    for (int k = 0; k < SPW; ++k) {
      float xk = O + P[k];
      float rcpA = fminf(fexp2(-xk), RCPEPS);
      float aprev = fexp2(xk);
      float gb = sg[dl * LCP + base + k] * sxpT[(1 + s) * PSX + base + k];
      S = fmaf(gb, rcpA, S);
      float h = aprev * S;
      float contrib = sxpT[(17 + s) * PSX + base + k] * h;
      contrib += __shfl_xor(contrib, 8);
      contrib += __shfl_xor(contrib, 4);
      contrib += __shfl_xor(contrib, 2);
      contrib += __shfl_xor(contrib, 1);
      if (s == 0)
        sys[dl * LCP + base + k] = contrib + Dd * sxs[dl * LCP + base + k];
    }
    cs2_carry += Wall;
    S_carry += Vall;
    __syncthreads();
    // ---- store sys (shares interval with next chunk's staging) ----
    for (int slot = tid; slot < 4 * (LC / 8); slot += 1024) {
      int c = slot >> 6, seg = slot & 63;
      bf16 tmp[8];
#pragma unroll
      for (int j = 0; j < 8; ++j) tmp[j] = __float2bfloat16(sys[c * LCP + seg * 8 + j]);
      u32x4v vv;
      vv.x = ((unsigned int*)tmp)[0]; vv.y = ((unsigned int*)tmp)[1];
      vv.z = ((unsigned int*)tmp)[2]; vv.w = ((unsigned int*)tmp)[3];
      __builtin_nontemporal_store(vv,
          (u32x4v*)(xsT + (size_t)(d0 + c) * L_SEQ + l0 + seg * 8));
    }
    // no trailing barrier: store (reads sys) and next staging (writes
    // sxpT/sxs) touch disjoint LDS; next readers are behind 2 barriers.
  }
}

extern "C" void kernel_launch(void* const* d_in, const int* in_sizes, int n_in,
                              void* d_out, int out_size, void* d_ws, size_t ws_size,
                              hipStream_t stream) {
  const float* x       = (const float*)d_in[0];
  const float* W_in    = (const float*)d_in[1];
  const float* conv_w  = (const float*)d_in[2];
  const float* conv_b  = (const float*)d_in[3];
  const float* W_xproj = (const float*)d_in[4];
  const float* dt_w    = (const float*)d_in[5];
  const float* dt_b    = (const float*)d_in[6];
  const float* A_log   = (const float*)d_in[7];
  const float* Dvec    = (const float*)d_in[8];
  const float* W_out   = (const float*)d_in[9];
  float* out = (float*)d_out;

  char* ws = (char*)d_ws;
  const size_t MB = 1024 * 1024;
  bf16* xz    = (bf16*)(ws);             // [2048][2048]
  bf16* buf1  = (bf16*)(ws + 8 * MB);    // [2048][1024] xs, later gated ys
  bf16* WinT  = (bf16*)(ws + 12 * MB);   // [2048][512] (dead after gemm1)
  bf16* xbf   = (bf16*)(ws + 14 * MB);   // [2048][512] x cast (dead after gemm1)
  bf16* xsT   = (bf16*)(ws + 12 * MB);   // [1024][2048] overlays WinT+xbf
  bf16* WoutT = (bf16*)(ws + 12 * MB);   // [512][1024] overlays dead xsT (late)
  float* xpcT = (float*)(ws + 16 * MB);  // [33][2048]

  // 1) WinT = W_in^T bf16; xbf = bf16(x)
  transpose_cast_kernel<<<dim3(2 * DI / 32, DM / 32), 256, 0, stream>>>(
      W_in, WinT, DM, 2 * DI);
  cast_f32_bf16_kernel<<<dim3(L_SEQ * DM / (256 * 8)), 256, 0, stream>>>(
      x, xbf, L_SEQ * DM / 8);
  // 2) xz = x @ W_in  (128x128 tile, grid 16x16 = 256 blocks)
  gemm_gl<4, 4, bf16><<<dim3(2 * DI / 128, L_SEQ / 128), 256, 0, stream>>>(
      xbf, WinT, xz, DM, DM, 2 * DI);
  // 3) conv + silu -> buf1[l][d] AND xsT[d][l]  (WinT, xbf dead)
  conv_silu_dual<<<dim3(DI / 64, L_SEQ / 64), 256, 0, stream>>>(
      xz, conv_w, conv_b, buf1, xsT);
  // 4) xpcT = (xs @ W_xproj)^T
  gemm_xproj<<<dim3(1, L_SEQ / 64), 256, 0, stream>>>(buf1, W_xproj, xpcT);
  // 5) scan: un-gated yT in place over xsT
  scan_kernel<<<DI / 4, 1024, 0, stream>>>(xsT, xpcT, dt_w, dt_b, A_log, Dvec);
  // 6) gate + transpose: ys[l][d] = yT * silu(z), z = xz cols 1024.. (ld 2048)
  gate_transpose_kernel<<<dim3(L_SEQ / 64, DI / 64), 256, 0, stream>>>(
      xsT, xz + DI, 2 * DI, buf1);
  // 7) WoutT = W_out^T bf16 (xsT dead now)
  transpose_cast_kernel<<<dim3(DM / 32, DI / 32), 256, 0, stream>>>(
      W_out, WoutT, DI, DM);
  // 8) out = ys @ W_out  (64x64 tile, grid 8x32 = 256 blocks)
  gemm_gl<2, 2, float><<<dim3(DM / 64, L_SEQ / 64), 256, 0, stream>>>(
      buf1, WoutT, out, DI, DI, DM);
}

// Round 7
// 190.360 us; speedup vs baseline: 1.1875x; 1.1482x over previous
//
#include <hip/hip_runtime.h>
#include <hip/hip_bf16.h>

// SelectiveSSM: B=1, L=2048, D_MODEL=512, D_INNER=1024, D_STATE=16, D_CONV=4
// ESTABLISHED: inputs fp32, d_out fp32, ws >= 17.05MB (R6 fp32 path ran).
// R17 (216us): scan serial-chain removal (exclusive log-prefix P[k]).
// R20 (221us): scan floor 62us, no spill (VGPR 64, WRITE 10MB).
// R21 (218us, NEUTRAL): dbuf gload_lds GEMMs only -3us -> GEMMs were never
// the ~155us non-scan bulk. Work accounting says ~50us of real work; rest is
// per-dispatch overhead (scan FETCH=its entire input: HBM round-trips between
// dispatches, cross-XCD L2 non-coherent) + xproj's 32-block occupancy hole.
// R22: dispatches 9->7 (prep = WinT+xcast merged; W_out transpose rides gate's
// spare blocks, WoutT overlays dead xpcT @16MB) + xproj split-K (8x32=256
// blocks, 4 K-steps, atomicAdd into xpcT zeroed by conv).
// R23: identical resubmit (R22 bench was an infra failure: container acquire
// failed twice; source audited clean - no OOB, no sync-in-divergent-branch,
// no graph-capture violation).
// ws 17.0MB: xz 8MB@0 | buf1 4MB@8 | 12-16MB: WinT 2MB + xbf 2MB@14 -> xsT
// 4MB -> (dead) | xpcT 264KB@16MB -> WoutT 1MB@16MB (after scan).

#define L_SEQ 2048
#define DM 512
#define DI 1024
#define DS 16
#define NXP 33
#define EPS 1e-10f
#define RCPEPS 1e10f
#define LOG2E 1.44269504088896340736f
#define LN2 0.69314718055994530942f
#define LOG2EPS -33.219280948873623478f  // log2(1e-10)

typedef __hip_bfloat16 bf16;
typedef __attribute__((ext_vector_type(8))) short bf16x8v;
typedef __attribute__((ext_vector_type(4))) float f32x4v;
typedef __attribute__((ext_vector_type(4))) unsigned int u32x4v;

__device__ __forceinline__ void st1(float* p, float v) { *p = v; }
__device__ __forceinline__ void st1(bf16* p, float v) { *p = __float2bfloat16(v); }

__device__ __forceinline__ float fexp2(float x) { return __builtin_amdgcn_exp2f(x); }
__device__ __forceinline__ float frcp(float x) { return __builtin_amdgcn_rcpf(x); }

__device__ __forceinline__ void load8(const float* p, float* v) {
  float4 a = *(const float4*)p;
  float4 b = *(const float4*)(p + 4);
  v[0] = a.x; v[1] = a.y; v[2] = a.z; v[3] = a.w;
  v[4] = b.x; v[5] = b.y; v[6] = b.z; v[7] = b.w;
}

// ---------- prep: W_in^T (blocks 0..1023) + x cast (blocks 1024..1535) ----
__global__ __launch_bounds__(256)
void prep_kernel(const float* __restrict__ W_in, bf16* __restrict__ WinT,
                 const float* __restrict__ x, bf16* __restrict__ xbf) {
  __shared__ float tile[32][33];
  int b = blockIdx.x;
  if (b < 1024) {
    int c0 = (b & 63) * 32, r0 = (b >> 6) * 32;  // C=2048 (64 tiles), R=512 (16)
    int tx = threadIdx.x & 31, ty = threadIdx.x >> 5;
#pragma unroll
    for (int i = 0; i < 4; ++i) {
      int rr = ty + i * 8;
      tile[rr][tx] = W_in[(size_t)(r0 + rr) * (2 * DI) + c0 + tx];
    }
    __syncthreads();
#pragma unroll
    for (int i = 0; i < 4; ++i) {
      int cc = ty + i * 8;
      WinT[(size_t)(c0 + cc) * DM + r0 + tx] = __float2bfloat16(tile[tx][cc]);
    }
  } else {
    int i = (b - 1024) * 256 + threadIdx.x;  // < 131072 = L*DM/8 exactly
    float v[8];
    load8(x + (size_t)i * 8, v);
    bf16 o[8];
#pragma unroll
    for (int j = 0; j < 8; ++j) o[j] = __float2bfloat16(v[j]);
    *(uint4*)(xbf + (size_t)i * 8) = *(uint4*)o;
  }
}

// ---------- 2-phase double-buffered gload_lds GEMM (R21-proven) ----------
// C[M][N] = A[M][K] @ BT[N][K]^T. A,BT bf16. 256 thr = 4 waves (2x2).
template <int WM, int WN, typename TC>
__global__ __launch_bounds__(256)
void gemm_gl(const bf16* __restrict__ A, const bf16* __restrict__ BT,
             TC* __restrict__ C, int K, int lda, int ldc) {
  constexpr int BM = 2 * WM * 16, BN = 2 * WN * 16;
  __shared__ __align__(16) bf16 As[2][BM * 32];
  __shared__ __align__(16) bf16 Bs[2][BN * 32];
  const int tid = threadIdx.x;
  const int wave = tid >> 6, lane = tid & 63;
  const int q = lane >> 4, r = lane & 15;
  const int wr = wave >> 1, wc = wave & 1;
  const int row0 = blockIdx.y * BM, col0 = blockIdx.x * BN;
  f32x4v acc[WM][WN] = {};
  const int nt = K / 32;

  auto stage = [&](int buf, int t) {
    int k0 = t * 32;
#pragma unroll
    for (int i = 0; i < BM / 64; ++i) {
      int slot = tid + i * 256;
      int row = slot >> 2, seg = slot & 3;
      __builtin_amdgcn_global_load_lds(
          (const __attribute__((address_space(1))) void*)(
              A + (size_t)(row0 + row) * lda + k0 + seg * 8),
          (__attribute__((address_space(3))) void*)&As[buf][row * 32 + seg * 8],
          16, 0, 0);
    }
#pragma unroll
    for (int i = 0; i < BN / 64; ++i) {
      int slot = tid + i * 256;
      int row = slot >> 2, seg = slot & 3;
      __builtin_amdgcn_global_load_lds(
          (const __attribute__((address_space(1))) void*)(
              BT + (size_t)(col0 + row) * K + k0 + seg * 8),
          (__attribute__((address_space(3))) void*)&Bs[buf][row * 32 + seg * 8],
          16, 0, 0);
    }
  };

  stage(0, 0);
  __syncthreads();
  int cur = 0;
  for (int t = 0; t < nt; ++t) {
    if (t + 1 < nt) stage(cur ^ 1, t + 1);
    bf16x8v a[WM], b[WN];
#pragma unroll
    for (int m = 0; m < WM; ++m)
      a[m] = *(const bf16x8v*)&As[cur][(wr * WM * 16 + m * 16 + r) * 32 + q * 8];
#pragma unroll
    for (int n = 0; n < WN; ++n)
      b[n] = *(const bf16x8v*)&Bs[cur][(wc * WN * 16 + n * 16 + r) * 32 + q * 8];
#pragma unroll
    for (int m = 0; m < WM; ++m)
#pragma unroll
      for (int n = 0; n < WN; ++n)
        acc[m][n] = __builtin_amdgcn_mfma_f32_16x16x32_bf16(a[m], b[n],
                                                            acc[m][n], 0, 0, 0);
    __syncthreads();
    cur ^= 1;
  }
#pragma unroll
  for (int m = 0; m < WM; ++m)
#pragma unroll
    for (int n = 0; n < WN; ++n)
#pragma unroll
      for (int reg = 0; reg < 4; ++reg) {
        int mm = row0 + wr * WM * 16 + m * 16 + q * 4 + reg;
        int nn = col0 + wc * WN * 16 + n * 16 + r;
        st1(C + (size_t)mm * ldc + nn, acc[m][n][reg]);
      }
}

// ---------- xproj split-K: xpcT[j][l] += partial over K-chunk ----------
// grid (8, 32): blockIdx.x = 128-wide K chunk, blockIdx.y = 64-row l tile.
// xpcT must be zeroed beforehand (conv does it).
__global__ __launch_bounds__(256)
void gemm_xproj_sk(const bf16* __restrict__ A, const float* __restrict__ Wx,
                   float* __restrict__ xpcT) {
  __shared__ __align__(16) bf16 As[64 * 40];
  __shared__ __align__(16) bf16 Bs[64 * 40];
  const int tid = threadIdx.x;
  const int wave = tid >> 6, lane = tid & 63;
  const int q = lane >> 4, r = lane & 15;
  const int row0 = blockIdx.y * 64;
  const int kb = blockIdx.x * 128;
  const int srow = tid >> 2, sseg = tid & 3;
  f32x4v acc[4] = {};
  for (int k0 = kb; k0 < kb + 128; k0 += 32) {
    *(uint4*)&As[srow * 40 + sseg * 8] =
        *(const uint4*)(A + (size_t)(row0 + srow) * DI + k0 + sseg * 8);
    int k = tid >> 3, n0 = (tid & 7) * 8;
#pragma unroll
    for (int j = 0; j < 8; ++j) {
      int n = n0 + j;
      float v = (n < NXP) ? Wx[(size_t)(k0 + k) * NXP + n] : 0.f;
      Bs[n * 40 + k] = __float2bfloat16(v);
    }
    __syncthreads();
    bf16x8v a = *(const bf16x8v*)&As[(wave * 16 + r) * 40 + q * 8];
#pragma unroll
    for (int j = 0; j < 4; ++j) {
      bf16x8v b = *(const bf16x8v*)&Bs[(j * 16 + r) * 40 + q * 8];
      acc[j] = __builtin_amdgcn_mfma_f32_16x16x32_bf16(a, b, acc[j], 0, 0, 0);
    }
    __syncthreads();
  }
#pragma unroll
  for (int j = 0; j < 4; ++j)
#pragma unroll
    for (int reg = 0; reg < 4; ++reg) {
      int m = row0 + wave * 16 + q * 4 + reg;
      int n = j * 16 + r;
      if (n < NXP) atomicAdd(&xpcT[(size_t)n * L_SEQ + m], acc[j][reg]);
    }
}

// ---------- conv + silu, dual-layout output; also zeroes xpcT ----------
__global__ __launch_bounds__(256)
void conv_silu_dual(const bf16* __restrict__ xz, const float* __restrict__ conv_w,
                    const float* __restrict__ conv_b, bf16* __restrict__ xs,
                    bf16* __restrict__ xsT, float* __restrict__ xpcT) {
  __shared__ bf16 tile[67][72];   // rows l0-3 .. l0+63
  __shared__ bf16 sout[64][72];   // [d][l]
  const int tid = threadIdx.x;
  const int d0 = blockIdx.x * 64, l0 = blockIdx.y * 64;
  // zero xpcT slice (512 blocks x 132 = 67584 = 33*2048)
  {
    int zb = blockIdx.y * gridDim.x + blockIdx.x;
    if (tid < 132) xpcT[(size_t)zb * 132 + tid] = 0.f;
  }
  // stage 67 rows x 64 cols
  for (int slot = tid; slot < 67 * 8; slot += 256) {
    int rr = slot >> 3, seg = slot & 7;
    int l = l0 - 3 + rr;
    uint4 v = {0, 0, 0, 0};
    if (l >= 0) v = *(const uint4*)(xz + (size_t)l * (2 * DI) + d0 + seg * 8);
    *(uint4*)&tile[rr][seg * 8] = v;
  }
  __syncthreads();
  {
    int lr = tid >> 3, c0t = (tid & 7) * 8;
#pragma unroll
    for (int half = 0; half < 2; ++half) {
      int lrow = lr + half * 32;
      bf16 o[8];
#pragma unroll
      for (int j = 0; j < 8; ++j) {
        int c = c0t + j;
        float acc = conv_b[d0 + c];
#pragma unroll
        for (int k = 0; k < 4; ++k)
          acc = fmaf(__bfloat162float(tile[lrow + k][c]), conv_w[(d0 + c) * 4 + k], acc);
        float v = acc / (1.f + __expf(-acc));
        o[j] = __float2bfloat16(v);
        sout[c][lrow] = o[j];
      }
      *(uint4*)(xs + (size_t)(l0 + lrow) * DI + d0 + c0t) = *(uint4*)o;
    }
  }
  __syncthreads();
  for (int slot = tid; slot < 64 * 8; slot += 256) {
    int dd = slot >> 3, seg = slot & 7;
    *(uint4*)(xsT + (size_t)(d0 + dd) * L_SEQ + l0 + seg * 8) =
        *(uint4*)&sout[dd][seg * 8];
  }
}

// ---------- gate (by<16) + W_out transpose (by>=16) ----------
// gate: ys[l][d] = yT[d][l] * silu(z[l][d]). transpose: WoutT[n][k]=W_out[k][n].
__global__ __launch_bounds__(256)
void gate_wt_kernel(const bf16* __restrict__ yT, const bf16* __restrict__ zbuf,
                    int ldz, bf16* __restrict__ ys,
                    const float* __restrict__ W_out, bf16* __restrict__ WoutT) {
  __shared__ bf16 tile[64][72];
  __shared__ float ttile[32][33];
  if (blockIdx.y >= 16) {
    int tb = (blockIdx.y - 16) * 32 + blockIdx.x;  // 0..511
    int c0 = (tb & 15) * 32, r0 = (tb >> 4) * 32;  // C=DM (16 tiles), R=DI (32)
    int tx = threadIdx.x & 31, ty = threadIdx.x >> 5;
#pragma unroll
    for (int i = 0; i < 4; ++i) {
      int rr = ty + i * 8;
      ttile[rr][tx] = W_out[(size_t)(r0 + rr) * DM + c0 + tx];
    }
    __syncthreads();
#pragma unroll
    for (int i = 0; i < 4; ++i) {
      int cc = ty + i * 8;
      WoutT[(size_t)(c0 + cc) * DI + r0 + tx] = __float2bfloat16(ttile[tx][cc]);
    }
    return;
  }
  int d0 = blockIdx.y * 64, l0 = blockIdx.x * 64;
#pragma unroll
  for (int it = 0; it < 2; ++it) {
    int slot = threadIdx.x + it * 256;
    int dd = slot >> 3, seg = slot & 7;
    *(uint4*)&tile[dd][seg * 8] = *(const uint4*)(yT + (size_t)(d0 + dd) * L_SEQ + l0 + seg * 8);
  }
  __syncthreads();
#pragma unroll
  for (int it = 0; it < 2; ++it) {
    int slot = threadIdx.x + it * 256;
    int ll = slot >> 3, seg = slot & 7;
    bf16 zt[8];
    *(uint4*)zt = *(const uint4*)(zbuf + (size_t)(l0 + ll) * ldz + d0 + seg * 8);
    bf16 o[8];
#pragma unroll
    for (int j = 0; j < 8; ++j) {
      float yv = __bfloat162float(tile[seg * 8 + j][ll]);
      float zv = __bfloat162float(zt[j]);
      o[j] = __float2bfloat16(yv * zv * frcp(1.f + fexp2(-zv * LOG2E)));
    }
    *(uint4*)(ys + (size_t)(l0 + ll) * DI + d0 + seg * 8) = *(uint4*)o;
  }
}

// ---------- chunk-parallel scan (R20-proven: 62us, VGPR 64, no spill) ----------
#define LC 512
#define NW 16
#define SPW 32
#define PSX 513
#define LCP 516

__global__ __launch_bounds__(1024)
void scan_kernel(bf16* __restrict__ xsT, const float* __restrict__ xpcT,
                 const float* __restrict__ dt_w, const float* __restrict__ dt_b,
                 const float* __restrict__ A_log, const float* __restrict__ Dvec) {
  __shared__ float sxpT[NXP * PSX];
  __shared__ float sdt[4 * LCP], sg[4 * LCP], sxs[4 * LCP];
  __shared__ float sys[4 * LCP];
  __shared__ float Wtot[NW][64], Vtot[NW][64];
  const int tid = threadIdx.x;
  const int wave = tid >> 6, lane = tid & 63;
  const int s = lane & 15, dl = lane >> 4;
  const int d0 = blockIdx.x * 4;
  const int base = wave * SPW;
  const float As2 = -expf(A_log[s]) * LOG2E;
  const float Dd = Dvec[d0 + dl];
  float dtw[4], dtb[4];
#pragma unroll
  for (int c = 0; c < 4; ++c) {
    dtw[c] = dt_w[d0 + c];
    dtb[c] = dt_b[d0 + c];
  }
  float cs2_carry = 0.f, S_carry = 0.f;
  for (int l0 = 0; l0 < L_SEQ; l0 += LC) {
    for (int idx = tid; idx < NXP * LC; idx += 1024) {
      int u = __builtin_amdgcn_readfirstlane(idx & ~63);
      int j = u >> 9, lb = u & (LC - 1);
      const float* gp = xpcT + (size_t)j * L_SEQ + l0 + lb + lane;
      __builtin_amdgcn_global_load_lds(
          (const __attribute__((address_space(1))) void*)gp,
          (__attribute__((address_space(3))) void*)&sxpT[j * PSX + lb], 4, 0, 0);
    }
    for (int slot = tid; slot < 4 * (LC / 8); slot += 1024) {
      int c = slot >> 6, seg = slot & 63;
      bf16 tmp[8];
      *(uint4*)tmp = *(const uint4*)(xsT + (size_t)(d0 + c) * L_SEQ + l0 + seg * 8);
#pragma unroll
      for (int j = 0; j < 8; ++j) sxs[c * LCP + seg * 8 + j] = __bfloat162float(tmp[j]);
    }
    __syncthreads();
    for (int idx = tid; idx < 4 * LC; idx += 1024) {
      int c = idx >> 9, i = idx & (LC - 1);
      float x0 = sxpT[i];
      float a = fmaf(x0, dtw[c], dtb[c]);
      float dt = __log2f(1.f + fexp2(a * LOG2E)) * LN2;
      sdt[c * LCP + i] = dt;
      sg[c * LCP + i] = dt * sxs[c * LCP + i];
    }
    __syncthreads();
    float P[SPW];
    float Wl = 0.f;
#pragma unroll
    for (int k = 0; k < SPW; ++k) {
      float u = sdt[dl * LCP + base + k] * As2;
      P[k] = Wl;
      Wl += fmaxf(u, LOG2EPS);
    }
    Wtot[wave][lane] = Wl;
    __syncthreads();
    float O = cs2_carry, Wall = 0.f;
    for (int w = 0; w < NW; ++w) {
      float t = Wtot[w][lane];
      if (w < wave) O += t;
      Wall += t;
    }
    float Vl = 0.f;
#pragma unroll
    for (int k = 0; k < SPW; ++k) {
      float rcpA = fminf(fexp2(-(O + P[k])), RCPEPS);
      float gb = sg[dl * LCP + base + k] * sxpT[(1 + s) * PSX + base + k];
      Vl = fmaf(gb, rcpA, Vl);
    }
    Vtot[wave][lane] = Vl;
    __syncthreads();
    float SO = S_carry, Vall = 0.f;
    for (int w = 0; w < NW; ++w) {
      float tv = Vtot[w][lane];
      if (w < wave) SO += tv;
      Vall += tv;
    }
    float S = SO;
#pragma unroll
    for (int k = 0; k < SPW; ++k) {
      float xk = O + P[k];
      float rcpA = fminf(fexp2(-xk), RCPEPS);
      float aprev = fexp2(xk);
      float gb = sg[dl * LCP + base + k] * sxpT[(1 + s) * PSX + base + k];
      S = fmaf(gb, rcpA, S);
      float h = aprev * S;
      float contrib = sxpT[(17 + s) * PSX + base + k] * h;
      contrib += __shfl_xor(contrib, 8);
      contrib += __shfl_xor(contrib, 4);
      contrib += __shfl_xor(contrib, 2);
      contrib += __shfl_xor(contrib, 1);
      if (s == 0)
        sys[dl * LCP + base + k] = contrib + Dd * sxs[dl * LCP + base + k];
    }
    cs2_carry += Wall;
    S_carry += Vall;
    __syncthreads();
    for (int slot = tid; slot < 4 * (LC / 8); slot += 1024) {
      int c = slot >> 6, seg = slot & 63;
      bf16 tmp[8];
#pragma unroll
      for (int j = 0; j < 8; ++j) tmp[j] = __float2bfloat16(sys[c * LCP + seg * 8 + j]);
      u32x4v vv;
      vv.x = ((unsigned int*)tmp)[0]; vv.y = ((unsigned int*)tmp)[1];
      vv.z = ((unsigned int*)tmp)[2]; vv.w = ((unsigned int*)tmp)[3];
      __builtin_nontemporal_store(vv,
          (u32x4v*)(xsT + (size_t)(d0 + c) * L_SEQ + l0 + seg * 8));
    }
    // no trailing barrier: store (reads sys) and next staging (writes
    // sxpT/sxs) touch disjoint LDS; next readers are behind 2 barriers.
  }
}

extern "C" void kernel_launch(void* const* d_in, const int* in_sizes, int n_in,
                              void* d_out, int out_size, void* d_ws, size_t ws_size,
                              hipStream_t stream) {
  const float* x       = (const float*)d_in[0];
  const float* W_in    = (const float*)d_in[1];
  const float* conv_w  = (const float*)d_in[2];
  const float* conv_b  = (const float*)d_in[3];
  const float* W_xproj = (const float*)d_in[4];
  const float* dt_w    = (const float*)d_in[5];
  const float* dt_b    = (const float*)d_in[6];
  const float* A_log   = (const float*)d_in[7];
  const float* Dvec    = (const float*)d_in[8];
  const float* W_out   = (const float*)d_in[9];
  float* out = (float*)d_out;

  char* ws = (char*)d_ws;
  const size_t MB = 1024 * 1024;
  bf16* xz    = (bf16*)(ws);             // [2048][2048]
  bf16* buf1  = (bf16*)(ws + 8 * MB);    // [2048][1024] xs, later gated ys
  bf16* WinT  = (bf16*)(ws + 12 * MB);   // [2048][512] (dead after gemm1)
  bf16* xbf   = (bf16*)(ws + 14 * MB);   // [2048][512] x cast (dead after gemm1)
  bf16* xsT   = (bf16*)(ws + 12 * MB);   // [1024][2048] overlays WinT+xbf
  float* xpcT = (float*)(ws + 16 * MB);  // [33][2048] (dead after scan)
  bf16* WoutT = (bf16*)(ws + 16 * MB);   // [512][1024] overlays dead xpcT

  // 1) prep: WinT = W_in^T bf16 (1024 blocks) + xbf = bf16(x) (512 blocks)
  prep_kernel<<<dim3(1536), 256, 0, stream>>>(W_in, WinT, x, xbf);
  // 2) xz = x @ W_in  (128x128 tile, grid 16x16 = 256 blocks)
  gemm_gl<4, 4, bf16><<<dim3(2 * DI / 128, L_SEQ / 128), 256, 0, stream>>>(
      xbf, WinT, xz, DM, DM, 2 * DI);
  // 3) conv + silu -> buf1[l][d] AND xsT[d][l]; zeroes xpcT  (WinT, xbf dead)
  conv_silu_dual<<<dim3(DI / 64, L_SEQ / 64), 256, 0, stream>>>(
      xz, conv_w, conv_b, buf1, xsT, xpcT);
  // 4) xpcT += (xs @ W_xproj)^T  (split-K, 256 blocks)
  gemm_xproj_sk<<<dim3(8, L_SEQ / 64), 256, 0, stream>>>(buf1, W_xproj, xpcT);
  // 5) scan: un-gated yT in place over xsT
  scan_kernel<<<DI / 4, 1024, 0, stream>>>(xsT, xpcT, dt_w, dt_b, A_log, Dvec);
  // 6) gate (512 blocks) + WoutT = W_out^T (512 blocks); xpcT dead -> WoutT
  gate_wt_kernel<<<dim3(L_SEQ / 64, 2 * DI / 64), 256, 0, stream>>>(
      xsT, xz + DI, 2 * DI, buf1, W_out, WoutT);
  // 7) out = ys @ W_out  (64x64 tile, grid 8x32 = 256 blocks)
  gemm_gl<2, 2, float><<<dim3(DM / 64, L_SEQ / 64), 256, 0, stream>>>(
      buf1, WoutT, out, DI, DI, DM);
}